// Round 6
// baseline (5095.525 us; speedup 1.0000x reference)
//
#include <hip/hip_runtime.h>
#include <hip/hip_bf16.h>

typedef __bf16 bf16x8 __attribute__((ext_vector_type(8)));
typedef float floatx4 __attribute__((ext_vector_type(4)));

#define GLB_AS __attribute__((address_space(1)))
#define LDS_AS __attribute__((address_space(3)))

__device__ __forceinline__ void async_cp16(const void* g, void* l) {
  // 16B/lane direct global->LDS DMA (global_load_lds_dwordx4), no VGPR payload.
  // LDS dest = wave-uniform base + lane*16; our seg layout guarantees it.
  __builtin_amdgcn_global_load_lds((GLB_AS void*)g, (LDS_AS void*)l, 16, 0, 0);
}

__device__ __forceinline__ unsigned short f2bf(float f) {
  __bf16 b = (__bf16)f;
  return __builtin_bit_cast(unsigned short, b);
}

// ---------------------------------------------------------------------------
// Kernel 1: decode w1 bits -> bf16 {-1,0,+1} in a SWIZZLED fragment-major
// layout (K padded 784->800 with zeros; j=98,99 groups write the zero pad):
//   off(row r, col c) = ((r>>4)*25 + (c>>5))*512 + (r&15)*32 + (c&31)
// -> each (16-row tile, 32-col chunk) is one contiguous 1KB run, so the
// GEMM's B-loads are perfectly coalesced 1KB wave-loads.
// ---------------------------------------------------------------------------
__global__ void decode_w1_kernel(const int* __restrict__ w1p,
                                 const int* __restrict__ m1p,
                                 unsigned short* __restrict__ w1d) {
  int t = blockIdx.x * 256 + threadIdx.x;
  if (t >= 256 * 100) return;
  int r = t / 100;
  int j = t - r * 100;
  unsigned short vals[8];
#pragma unroll
  for (int k = 0; k < 8; ++k) vals[k] = 0;
  if (j < 98) {
    unsigned int v = (unsigned int)w1p[r * 98 + j];
    unsigned int m = (unsigned int)m1p[r * 98 + j];
#pragma unroll
    for (int k = 0; k < 8; ++k) {           // MSB-first per byte (matches _unpack)
      unsigned int bit = (v >> (7 - k)) & 1u;
      unsigned int mk  = (m >> (7 - k)) & 1u;
      vals[k] = (unsigned short)(mk ? (bit ? 0x3F80u : 0xBF80u) : 0u);
    }
  }
  uint4 pack;
  pack.x = (unsigned)vals[0] | ((unsigned)vals[1] << 16);
  pack.y = (unsigned)vals[2] | ((unsigned)vals[3] << 16);
  pack.z = (unsigned)vals[4] | ((unsigned)vals[5] << 16);
  pack.w = (unsigned)vals[6] | ((unsigned)vals[7] << 16);
  int c0   = j * 8;                          // 16B-aligned (c0&31 in {0,8,16,24})
  int off  = (((r >> 4) * 25 + (c0 >> 5)) << 9) + ((r & 15) << 5) + (c0 & 31);
  *reinterpret_cast<uint4*>(w1d + off) = pack;
}

// ---------------------------------------------------------------------------
// Kernel 2: fused  h = relu(a1 * x@W1^T);  out = a2 * (h@W2^T)
// R6: VGPR-free deep-MLP staging.
//  * BM=16: block's 16 x rows = ONE contiguous 50176B range, DMA'd raw fp32
//    into LDS via 49 global_load_lds_dwordx4 instrs, ALL in flight at once
//    (no dependent chain, no VGPR payload -> no spill).
//  * fp32->bf16 conversion moved into the K-loop (VALU was ~9% busy).
//  * K-loop barrier-free: A from fp32 slab (zeroed for ko>=784 tail),
//    B = coalesced 1KB wave-loads from swizzled L2-resident w1d, clamped
//    distance-2 register prefetch (parity double-buffer).
//  * LDS 50.2KB -> 3 blocks/CU = 12 waves/CU; 2048 blocks ping-pong
//    staging vs compute per CU.
// 256 threads (4 waves); wave owns 16 rows x cols wave*64..+63 (4 n-tiles).
// mfma_f32_16x16x32_bf16: A[m=l15][k=quad*8+j], B^T[n=l15][k=quad*8+j],
// C/D col=l15, row=quad*4+reg (m89-verified).
// ---------------------------------------------------------------------------
#define W1TILE 12800  // shorts per 16-row swizzled tile: 25 chunks * 512
#define HS_LD 264
#define OFF_W2 (16 * HS_LD)   // shorts; W2s[16][264] after Hs[16][264] overlay

__global__ __launch_bounds__(256, 3) void fused_kernel(
    const float* __restrict__ x,
    const unsigned short* __restrict__ w1d,
    const int* __restrict__ w2p,
    const int* __restrict__ m2p,
    const float* __restrict__ a1p,
    const float* __restrict__ a2p,
    float* __restrict__ out) {
  // phase 1: x slab [16][784] fp32 = 50176 B (contiguous, no pad: DMA needs it)
  // phase 2 (overlay): Hs[16][264] + W2s[16][264] bf16 = 16896 B.
  __shared__ float slab[12544];
  unsigned short* hsm = reinterpret_cast<unsigned short*>(slab);

  const int tid  = threadIdx.x;
  const int wave = tid >> 6;    // 0..3
  const int lane = tid & 63;
  const int l15  = lane & 15;
  const int quad = lane >> 4;
  const int row0 = blockIdx.x * 16;

  // ---- phase 0: 49 async DMA instrs, wave-strided, all outstanding ----
  const float* xs = x + (size_t)row0 * 784;   // 50176 B contiguous
#pragma unroll
  for (int seg = wave; seg < 49; seg += 4)
    async_cp16(xs + seg * 256 + lane * 4, &slab[seg * 256 + lane * 4]);
  __syncthreads();   // drains vmcnt: slab complete

  // ---- K-loop: 25 chunks, barrier-free, B prefetch distance 2 ----
  const unsigned short* wb[4];
#pragma unroll
  for (int nj = 0; nj < 4; ++nj)
    wb[nj] = w1d + (size_t)(wave * 4 + nj) * W1TILE + l15 * 32 + quad * 8;

  floatx4 acc[4];
#pragma unroll
  for (int j = 0; j < 4; ++j) acc[j] = (floatx4){0.f, 0.f, 0.f, 0.f};

  bf16x8 bq[2][4];                          // [chunk parity][n-tile]
#pragma unroll
  for (int nj = 0; nj < 4; ++nj) {
    bq[0][nj] = *reinterpret_cast<const bf16x8*>(wb[nj]);
    bq[1][nj] = *reinterpret_cast<const bf16x8*>(wb[nj] + 512);
  }

#pragma unroll 1
  for (int kc = 0; kc < 25; ++kc) {
    const int p = kc & 1;
    bf16x8 c0 = bq[p][0], c1 = bq[p][1], c2 = bq[p][2], c3 = bq[p][3];
    int kf = kc + 2;                         // prefetch distance 2
    if (kf > 24) kf = 24;                    // clamped: in-bounds, no undef
#pragma unroll
    for (int nj = 0; nj < 4; ++nj)
      bq[p][nj] = *reinterpret_cast<const bf16x8*>(wb[nj] + kf * 512);

    const int ko = kc * 32 + quad * 8;
    float4 xa0, xa1;
    if (ko < 784) {                          // chunk 24, quads 2-3: K-pad -> 0
      xa0 = *reinterpret_cast<const float4*>(&slab[l15 * 784 + ko]);
      xa1 = *reinterpret_cast<const float4*>(&slab[l15 * 784 + ko + 4]);
    } else {
      xa0 = (float4){0.f, 0.f, 0.f, 0.f};
      xa1 = (float4){0.f, 0.f, 0.f, 0.f};
    }
    bf16x8 a;
    a[0] = (__bf16)xa0.x; a[1] = (__bf16)xa0.y;
    a[2] = (__bf16)xa0.z; a[3] = (__bf16)xa0.w;
    a[4] = (__bf16)xa1.x; a[5] = (__bf16)xa1.y;
    a[6] = (__bf16)xa1.z; a[7] = (__bf16)xa1.w;

    acc[0] = __builtin_amdgcn_mfma_f32_16x16x32_bf16(a, c0, acc[0], 0, 0, 0);
    acc[1] = __builtin_amdgcn_mfma_f32_16x16x32_bf16(a, c1, acc[1], 0, 0, 0);
    acc[2] = __builtin_amdgcn_mfma_f32_16x16x32_bf16(a, c2, acc[2], 0, 0, 0);
    acc[3] = __builtin_amdgcn_mfma_f32_16x16x32_bf16(a, c3, acc[3], 0, 0, 0);
  }

  __syncthreads();   // all slab reads done before Hs overlays it

  // ---- epilogue layer 1: h = relu(a1*acc) -> Hs[16][264] bf16 ----
  const float a1s = a1p[0];
  const float a2s = a2p[0];
#pragma unroll
  for (int nj = 0; nj < 4; ++nj) {
    int col = wave * 64 + nj * 16 + l15;
#pragma unroll
    for (int r = 0; r < 4; ++r) {
      float h = fmaxf(a1s * acc[nj][r], 0.f);
      hsm[(quad * 4 + r) * HS_LD + col] = f2bf(h);
    }
  }
  // ---- decode w2 -> W2s[16][264] (rows 10..15 zero) ----
#pragma unroll
  for (int it = 0; it < 2; ++it) {
    int idx = it * 256 + tid;
    if (idx < 320) {
      int r = idx >> 5, j = idx & 31;
      unsigned int vv = (unsigned int)w2p[r * 32 + j];
      unsigned int mm = (unsigned int)m2p[r * 32 + j];
#pragma unroll
      for (int k = 0; k < 8; ++k) {
        unsigned int bit = (vv >> (7 - k)) & 1u;
        unsigned int mk  = (mm >> (7 - k)) & 1u;
        hsm[OFF_W2 + r * HS_LD + j * 8 + k] =
            (unsigned short)(mk ? (bit ? 0x3F80u : 0xBF80u) : 0u);
      }
    }
  }
#pragma unroll
  for (int r = 10; r < 16; ++r) hsm[OFF_W2 + r * HS_LD + tid] = 0;
  __syncthreads();

  // ---- layer 2: out[16][10] = Hs @ W2s^T; wave 0, K=256 ----
  if (wave == 0) {
    floatx4 o2 = (floatx4){0.f, 0.f, 0.f, 0.f};
#pragma unroll
    for (int ks = 0; ks < 8; ++ks) {
      bf16x8 ha = *reinterpret_cast<const bf16x8*>(
          &hsm[l15 * HS_LD + ks * 32 + quad * 8]);
      bf16x8 wv = *reinterpret_cast<const bf16x8*>(
          &hsm[OFF_W2 + l15 * HS_LD + ks * 32 + quad * 8]);
      o2 = __builtin_amdgcn_mfma_f32_16x16x32_bf16(ha, wv, o2, 0, 0, 0);
    }
    if (l15 < 10) {
#pragma unroll
      for (int r = 0; r < 4; ++r) {
        int gr = row0 + quad * 4 + r;
        out[(size_t)gr * 10 + l15] = a2s * o2[r];
      }
    }
  }
}

extern "C" void kernel_launch(void* const* d_in, const int* in_sizes, int n_in,
                              void* d_out, int out_size, void* d_ws, size_t ws_size,
                              hipStream_t stream) {
  const float* x   = (const float*)d_in[0];
  const int*   w1p = (const int*)d_in[1];
  const int*   m1p = (const int*)d_in[2];
  const float* a1  = (const float*)d_in[3];
  const int*   w2p = (const int*)d_in[4];
  const int*   m2p = (const int*)d_in[5];
  const float* a2  = (const float*)d_in[6];
  unsigned short* w1d = (unsigned short*)d_ws;  // 256*800 bf16 = 400 KB scratch
  float* out = (float*)d_out;

  decode_w1_kernel<<<100, 256, 0, stream>>>(w1p, m1p, w1d);
  fused_kernel<<<2048, 256, 0, stream>>>(x, w1d, w2p, m2p, a1, a2, out);
}